// Round 1
// baseline (253.208 us; speedup 1.0000x reference)
//
#include <hip/hip_runtime.h>

// Y = X @ H, H = normalized 4096x4096 Sylvester-Hadamard (symmetric).
// Equivalent to a per-row Fast Walsh-Hadamard Transform scaled by 2^-6.
// Memory-bound: 256 MB traffic -> ~41 us roofline at 6.3 TB/s.

#define FWHT_N 4096   // transform size (2^12)
#define TPB    256    // threads per block (one block per row)
#define EPT    16     // elements per thread (TPB * EPT == FWHT_N)

// Padded LDS index: +1 float per 16 floats breaks the stride-16/256
// exchange patterns' power-of-2 bank aliasing (<=3-way worst case).
__device__ __forceinline__ int pad(int i) { return i + (i >> 4); }

// 4 butterfly stages over the 16 in-register elements (local strides 1,2,4,8).
__device__ __forceinline__ void bfly16(float v[EPT]) {
#pragma unroll
    for (int d = 1; d < EPT; d <<= 1) {
#pragma unroll
        for (int i = 0; i < EPT; ++i) {
            if ((i & d) == 0) {
                float u = v[i], w = v[i + d];
                v[i]     = u + w;
                v[i + d] = u - w;
            }
        }
    }
}

__global__ __launch_bounds__(TPB) void fwht4096_kernel(const float* __restrict__ X,
                                                       float* __restrict__ Y) {
    __shared__ float lds[FWHT_N + (FWHT_N >> 4)];  // 4352 floats = 17 KB

    const int t = threadIdx.x;
    const long long row = blockIdx.x;
    const float* __restrict__ x = X + row * FWHT_N;
    float*       __restrict__ y = Y + row * FWHT_N;

    float v[EPT];

    // ---- Phase A: thread t holds i = 16*t + a (a = local index, global bits 0..3)
    const float4* x4 = (const float4*)(x + (t << 4));
#pragma unroll
    for (int j = 0; j < 4; ++j) {
        float4 f = x4[j];
        v[4 * j + 0] = f.x; v[4 * j + 1] = f.y;
        v[4 * j + 2] = f.z; v[4 * j + 3] = f.w;
    }
    bfly16(v);  // global strides 1,2,4,8

    // ---- Exchange A->B: write contiguous chunks, read stride-16 sets
#pragma unroll
    for (int a2 = 0; a2 < EPT; ++a2) {
        int i = (t << 4) + a2;        // lds addr = 17*t + a2 -> 2-way, conflict-free
        lds[pad(i)] = v[a2];
    }
    __syncthreads();

    const int a = t & 15;
    const int c = t >> 4;
#pragma unroll
    for (int b = 0; b < EPT; ++b) {   // thread (a,c) holds i = a + 16*b + 256*c
        int i = a + (b << 4) + (c << 8);
        v[b] = lds[pad(i)];
    }
    bfly16(v);  // global strides 16,32,64,128 (local index = bits 4..7)

    // ---- Exchange B->C: each thread overwrites exactly the addresses it just
    // read (sets partition by (a,c)) -> no barrier needed before the writes.
#pragma unroll
    for (int b = 0; b < EPT; ++b) {
        int i = a + (b << 4) + (c << 8);
        lds[pad(i)] = v[b];
    }
    __syncthreads();

    const int b2 = t >> 4;            // thread t = a + 16*b2 holds stride-256 set
#pragma unroll
    for (int cc = 0; cc < EPT; ++cc) {
        int i = a + (b2 << 4) + (cc << 8);   // == t + 256*cc
        v[cc] = lds[pad(i)];
    }
    bfly16(v);  // global strides 256,512,1024,2048 (local index = bits 8..11)

    // ---- Store: y[t + 256*cc] -> each wave store = 256 B contiguous segment
    const float scale = 0.015625f;    // 2^(-12/2), the normalized-H factor
#pragma unroll
    for (int cc = 0; cc < EPT; ++cc) {
        y[t + (cc << 8)] = v[cc] * scale;
    }
}

extern "C" void kernel_launch(void* const* d_in, const int* in_sizes, int n_in,
                              void* d_out, int out_size, void* d_ws, size_t ws_size,
                              hipStream_t stream) {
    const float* X = (const float*)d_in[0];   // (ROWS, 4096) fp32
    // d_in[1] is the dense H matrix -- unused; we compute the FWHT directly.
    float* Y = (float*)d_out;                 // (ROWS, 4096) fp32
    const int rows = in_sizes[0] / FWHT_N;
    hipLaunchKernelGGL(fwht4096_kernel, dim3(rows), dim3(TPB), 0, stream, X, Y);
}